// Round 3
// baseline (448.741 us; speedup 1.0000x reference)
//
#include <hip/hip_runtime.h>
#include <hip/hip_bf16.h>

// SoftmaxAttention: B=64, Lc=Lr=512, D=768, fp32 in/out.
// Pipeline (per batch chunk):
//   k_prep   : X fp32 -> Xhi,Xlo bf16 (split, row-major) + XT bf16 (transposed)
//   k_gemm_s : S = (Chi+Clo)(Rhi+Rlo)^T via 3-term MFMA; writes S and ST
//   k_softmax: masked row-softmax of S -> Wc bf16, of ST -> Wr bf16
//   k_pv     : out_c = Wc@R * cmask ; out_r = Wr@C * rmask
// Mask semantics: w_j = m_j exp(t_j - M) / (S_act + EPS*Z),
//   t = s*m, M = max_j t_j (=max(max_act,0) if any inactive),
//   Z = S_act + n_inact*exp(-M), EPS=1e-13.

#define BATCH 64
#define LSEQ 512
#define DMODEL 768

typedef __attribute__((ext_vector_type(4))) float f32x4;
typedef __attribute__((ext_vector_type(8))) short bf16x8;
typedef __attribute__((ext_vector_type(4))) unsigned short u16x4;
typedef __attribute__((ext_vector_type(8))) unsigned short u16x8;

__device__ __forceinline__ unsigned short f2bf(float x) {
  union { float f; unsigned u; } v; v.f = x;
  unsigned r = v.u + 0x7FFFu + ((v.u >> 16) & 1u);
  return (unsigned short)(r >> 16);
}
__device__ __forceinline__ float bf2f(unsigned short h) {
  union { float f; unsigned u; } v; v.u = ((unsigned)h) << 16;
  return v.f;
}
__device__ __forceinline__ void gload16(const void* g, void* l) {
  __builtin_amdgcn_global_load_lds(
      (const __attribute__((address_space(1))) unsigned int*)g,
      (__attribute__((address_space(3))) unsigned int*)l, 16, 0, 0);
}

// ---- prep: X[b][512][768] fp32 -> Hi/Lo [bz][512][768] bf16 + XT [bz][768][512] bf16
// grid (8 n-tiles, 24: y<12 -> R d-tile y, y>=12 -> C d-tile y-12, nb)
__global__ __launch_bounds__(256) void k_prep(
    const float* __restrict__ Rg, const float* __restrict__ Cg,
    unsigned short* __restrict__ Rhi, unsigned short* __restrict__ Rlo,
    unsigned short* __restrict__ RT,
    unsigned short* __restrict__ Chi, unsigned short* __restrict__ Clo,
    unsigned short* __restrict__ CT, int b0) {
  __shared__ float tile[64][65];
  const int bz = blockIdx.z;
  int y = blockIdx.y;
  const float* X;
  unsigned short *Hi, *Lo, *XT;
  if (y < 12) { X = Rg; Hi = Rhi; Lo = Rlo; XT = RT; }
  else { y -= 12; X = Cg; Hi = Chi; Lo = Clo; XT = CT; }
  const int n0 = blockIdx.x * 64, d0 = y * 64;
  const int tid = threadIdx.x;
  const int i = tid >> 2, s4 = (tid & 3) * 4;
  const float* Xb = X + ((size_t)(b0 + bz) * LSEQ + n0 + i) * DMODEL + d0;
  unsigned short* Hb = Hi + ((size_t)bz * LSEQ + n0 + i) * DMODEL + d0;
  unsigned short* Lb = Lo + ((size_t)bz * LSEQ + n0 + i) * DMODEL + d0;
#pragma unroll
  for (int kk = 0; kk < 4; ++kk) {
    const int j = kk * 16 + s4;
    const f32x4 v = *(const f32x4*)(Xb + j);
    u16x4 h, l;
#pragma unroll
    for (int k = 0; k < 4; ++k) {
      h[k] = f2bf(v[k]);
      l[k] = f2bf(v[k] - bf2f(h[k]));
      tile[i][j + k] = v[k];
    }
    *(u16x4*)(Hb + j) = h;
    *(u16x4*)(Lb + j) = l;
  }
  __syncthreads();
  unsigned short* Ob = XT + ((size_t)bz * DMODEL + d0 + i) * LSEQ + n0;
#pragma unroll
  for (int kk = 0; kk < 4; ++kk) {
    const int n = kk * 16 + s4;
    u16x4 h;
#pragma unroll
    for (int k = 0; k < 4; ++k) h[k] = f2bf(tile[n + k][i]);
    *(u16x4*)(Ob + n) = h;
  }
}

// ---- S = C R^T (3-term split), 128x128 tile, BK=32, global_load_lds staging.
// Epilogue writes S[c][r] and ST[r][c]. grid (4 c-tiles, 4 r-tiles, nb)
__global__ __launch_bounds__(256) void k_gemm_s(
    const unsigned short* __restrict__ Chi, const unsigned short* __restrict__ Clo,
    const unsigned short* __restrict__ Rhi, const unsigned short* __restrict__ Rlo,
    float* __restrict__ S, float* __restrict__ ST) {
  __shared__ __align__(16) char smem[33280];
  unsigned short* AhiL = (unsigned short*)smem;           // 8 KB each
  unsigned short* AloL = (unsigned short*)(smem + 8192);
  unsigned short* BhiL = (unsigned short*)(smem + 16384);
  unsigned short* BloL = (unsigned short*)(smem + 24576);
  float* tbuf = (float*)smem;                             // epilogue alias: 2 x [64][65] f32
  const int bz = blockIdx.z;
  const int c0 = blockIdx.x * 128;
  const int r0 = blockIdx.y * 128;
  const int tid = threadIdx.x;
  const int lane = tid & 63;
  const int w = tid >> 6;
  const int wm = (w & 1) * 64, wr = (w >> 1) * 64;
  const int l15 = lane & 15, kg = lane >> 4;
  const unsigned short* Ah = Chi + ((size_t)bz * LSEQ + c0) * DMODEL;
  const unsigned short* Al = Clo + ((size_t)bz * LSEQ + c0) * DMODEL;
  const unsigned short* Bh = Rhi + ((size_t)bz * LSEQ + r0) * DMODEL;
  const unsigned short* Bl = Rlo + ((size_t)bz * LSEQ + r0) * DMODEL;
  f32x4 acc[4][4] = {};
  for (int k0 = 0; k0 < DMODEL; k0 += 32) {
    __syncthreads();  // prev iter's ds_reads done
#pragma unroll
    for (int q = 0; q < 2; ++q) {
      const int t2 = q * 256 + tid;
      const int row = t2 >> 2, cp = (t2 & 3) * 8;
      const size_t go = (size_t)row * DMODEL + k0 + cp;
      gload16(Ah + go, AhiL + t2 * 8);
      gload16(Al + go, AloL + t2 * 8);
      gload16(Bh + go, BhiL + t2 * 8);
      gload16(Bl + go, BloL + t2 * 8);
    }
    __syncthreads();  // drain global_load_lds
    bf16x8 ah[4], al[4], bh[4], bl[4];
#pragma unroll
    for (int f = 0; f < 4; ++f) {
      const int ar = (wm + f * 16 + l15) * 32 + kg * 8;
      const int br = (wr + f * 16 + l15) * 32 + kg * 8;
      ah[f] = *(const bf16x8*)(AhiL + ar);
      al[f] = *(const bf16x8*)(AloL + ar);
      bh[f] = *(const bf16x8*)(BhiL + br);
      bl[f] = *(const bf16x8*)(BloL + br);
    }
#pragma unroll
    for (int fm = 0; fm < 4; ++fm)
#pragma unroll
      for (int fr = 0; fr < 4; ++fr) {
        acc[fm][fr] = __builtin_amdgcn_mfma_f32_16x16x32_bf16(ah[fm], bh[fr], acc[fm][fr], 0, 0, 0);
        acc[fm][fr] = __builtin_amdgcn_mfma_f32_16x16x32_bf16(ah[fm], bl[fr], acc[fm][fr], 0, 0, 0);
        acc[fm][fr] = __builtin_amdgcn_mfma_f32_16x16x32_bf16(al[fm], bh[fr], acc[fm][fr], 0, 0, 0);
      }
  }
  const int g4 = (lane >> 4) * 4;
  float* Sb = S + ((size_t)bz * LSEQ + c0) * LSEQ + r0;
#pragma unroll
  for (int fm = 0; fm < 4; ++fm)
#pragma unroll
    for (int fr = 0; fr < 4; ++fr)
#pragma unroll
      for (int reg = 0; reg < 4; ++reg)
        Sb[(size_t)(wm + fm * 16 + g4 + reg) * LSEQ + wr + fr * 16 + l15] = acc[fm][fr][reg];
  // ST[r][c] via LDS transpose; phase p handles waves {2p, 2p+1} (wr = p*64)
  const int rr = tid >> 2;
  const int cb = (tid & 3) * 32;
#pragma unroll
  for (int p = 0; p < 2; ++p) {
    __syncthreads();  // staging reads (p=0) / prev phase reads (p=1) done
    if ((w >> 1) == p) {
      const int e = w & 1;
#pragma unroll
      for (int fm = 0; fm < 4; ++fm)
#pragma unroll
        for (int fr = 0; fr < 4; ++fr)
#pragma unroll
          for (int reg = 0; reg < 4; ++reg)
            tbuf[e * 4160 + (fm * 16 + g4 + reg) * 65 + fr * 16 + l15] = acc[fm][fr][reg];
    }
    __syncthreads();
    float* STb = ST + ((size_t)bz * LSEQ + r0 + p * 64 + rr) * LSEQ + c0;
#pragma unroll
    for (int q = 0; q < 8; ++q) {
      const int c4 = cb + q * 4;
      const int e = c4 >> 6, cl = c4 & 63;
      f32x4 v;
#pragma unroll
      for (int j = 0; j < 4; ++j) v[j] = tbuf[e * 4160 + (cl + j) * 65 + rr];
      *(f32x4*)(STb + c4) = v;
    }
  }
}

// ---- masked row-softmax: job 0: S->Wc (rmask), job 1: ST->Wr (cmask)
// grid (8 row-tiles, 2 jobs, nb); one wave handles 16 rows, row in registers
__global__ __launch_bounds__(256) void k_softmax(
    const float* __restrict__ Sg, const float* __restrict__ STg,
    const int* __restrict__ rmask, const int* __restrict__ cmask,
    unsigned short* __restrict__ WcG, unsigned short* __restrict__ WrG, int b0) {
  __shared__ float maskNf[LSEQ];
  __shared__ float s_ninact;
  const int job = blockIdx.y;
  const float* Lg = job ? STg : Sg;
  const int* maskN = job ? cmask : rmask;
  unsigned short* Wg = job ? WrG : WcG;
  const int bz = blockIdx.z;
  const int b = b0 + bz;
  const int r0 = blockIdx.x * 64;
  const int tid = threadIdx.x;
  const int lane = tid & 63;
  const int w = tid >> 6;
  if (tid == 0) s_ninact = 0.f;
  __syncthreads();
  float cnt = 0.f;
  for (int j = tid; j < LSEQ; j += 256) {
    const float m = (float)maskN[(size_t)b * LSEQ + j];
    maskNf[j] = m;
    cnt += 1.f - m;
  }
#pragma unroll
  for (int s = 1; s < 64; s <<= 1) cnt += __shfl_xor(cnt, s);
  if (lane == 0) atomicAdd(&s_ninact, cnt);
  __syncthreads();
  const float ninact = s_ninact;
  float mk[8];
#pragma unroll
  for (int k = 0; k < 8; ++k) mk[k] = maskNf[lane * 8 + k];

  for (int rrow = 0; rrow < 16; ++rrow) {
    const int r = r0 + w * 16 + rrow;
    const float* Lr = Lg + ((size_t)bz * LSEQ + r) * LSEQ + lane * 8;
    const f32x4 v0 = *(const f32x4*)(Lr);
    const f32x4 v1 = *(const f32x4*)(Lr + 4);
    float v[8];
#pragma unroll
    for (int k = 0; k < 4; ++k) { v[k] = v0[k]; v[k + 4] = v1[k]; }
    float mx = -1e30f;
#pragma unroll
    for (int k = 0; k < 8; ++k)
      if (mk[k] > 0.5f) mx = fmaxf(mx, v[k]);
#pragma unroll
    for (int s = 1; s < 64; s <<= 1) mx = fmaxf(mx, __shfl_xor(mx, s));
    const float M = (ninact > 0.5f) ? fmaxf(mx, 0.f) : mx;
    float p[8];
    float sum = 0.f;
#pragma unroll
    for (int k = 0; k < 8; ++k) {
      p[k] = mk[k] * __expf(fminf(v[k] - M, 0.f));
      sum += p[k];
    }
#pragma unroll
    for (int s = 1; s < 64; s <<= 1) sum += __shfl_xor(sum, s);
    const float Z = sum + ((ninact > 0.5f) ? ninact * __expf(-M) : 0.f);
    const float inv = 1.f / (sum + 1e-13f * Z);
    u16x8 h;
#pragma unroll
    for (int k = 0; k < 8; ++k) h[k] = f2bf(p[k] * inv);
    *(u16x8*)(Wg + ((size_t)bz * LSEQ + r) * LSEQ + lane * 8) = h;
  }
}

// ---- PV GEMM: out[b][m][d] = (sum_n W[m,n]*Vt[d,n]) * maskM[m]
// grid (4 m-tiles, 12: y<6 job c d-tile y, y>=6 job r d-tile y-6, nb)
__global__ __launch_bounds__(256) void k_pv(
    const unsigned short* __restrict__ WcG, const unsigned short* __restrict__ WrG,
    const unsigned short* __restrict__ RT, const unsigned short* __restrict__ CT,
    const int* __restrict__ cmask, const int* __restrict__ rmask,
    float* __restrict__ out, int b0) {
  __shared__ unsigned short Alds[128 * 32];
  __shared__ unsigned short Blds[128 * 32];
  __shared__ float maskMf[128];
  int y = blockIdx.y;
  const int job = (y >= 6) ? 1 : 0;
  if (job) y -= 6;
  const unsigned short* Wg = job ? WrG : WcG;
  const unsigned short* Vt = job ? CT : RT;
  const int* maskM = job ? rmask : cmask;
  float* outp = out + (job ? (size_t)BATCH * LSEQ * DMODEL : 0);
  const int bz = blockIdx.z;
  const int m0 = blockIdx.x * 128;
  const int d0 = y * 128;
  const int tid = threadIdx.x;
  const int lane = tid & 63;
  const int w = tid >> 6;
  const int wm = (w & 1) * 64, wd = (w >> 1) * 64;
  const int l15 = lane & 15, kg = lane >> 4;
  if (tid < 128) maskMf[tid] = (float)maskM[(size_t)(b0 + bz) * LSEQ + m0 + tid];
  const unsigned short* Wb = Wg + ((size_t)bz * LSEQ + m0) * LSEQ;
  const unsigned short* Vb = Vt + ((size_t)bz * DMODEL + d0) * LSEQ;
  f32x4 acc[4][4] = {};
  for (int k0 = 0; k0 < LSEQ; k0 += 32) {
    __syncthreads();
#pragma unroll
    for (int q = 0; q < 2; ++q) {
      const int t2 = q * 256 + tid;
      const int row = t2 >> 2, cp = (t2 & 3) * 8;
      gload16(Wb + (size_t)row * LSEQ + k0 + cp, &Alds[t2 * 8]);
      gload16(Vb + (size_t)row * LSEQ + k0 + cp, &Blds[t2 * 8]);
    }
    __syncthreads();
    bf16x8 a[4], bb[4];
#pragma unroll
    for (int f = 0; f < 4; ++f) {
      a[f]  = *(const bf16x8*)&Alds[(wm + f * 16 + l15) * 32 + kg * 8];
      bb[f] = *(const bf16x8*)&Blds[(wd + f * 16 + l15) * 32 + kg * 8];
    }
#pragma unroll
    for (int fm = 0; fm < 4; ++fm)
#pragma unroll
      for (int fd = 0; fd < 4; ++fd)
        acc[fm][fd] = __builtin_amdgcn_mfma_f32_16x16x32_bf16(a[fm], bb[fd], acc[fm][fd], 0, 0, 0);
  }
  const int g4 = (lane >> 4) * 4;
#pragma unroll
  for (int fm = 0; fm < 4; ++fm)
#pragma unroll
    for (int fd = 0; fd < 4; ++fd)
#pragma unroll
      for (int reg = 0; reg < 4; ++reg) {
        const int row = wm + fm * 16 + g4 + reg;
        const int col = wd + fd * 16 + l15;
        outp[((size_t)(b0 + bz) * LSEQ + m0 + row) * DMODEL + d0 + col] =
            acc[fm][fd][reg] * maskMf[row];
      }
}

extern "C" void kernel_launch(void* const* d_in, const int* in_sizes, int n_in,
                              void* d_out, int out_size, void* d_ws, size_t ws_size,
                              hipStream_t stream) {
  const float* context = (const float*)d_in[0];
  const float* response = (const float*)d_in[1];
  const int* cmask = (const int*)d_in[2];
  const int* rmask = (const int*)d_in[3];
  float* out = (float*)d_out;

  // per-batch ws: S+ST fp32 (2 MB) + Chi/Clo/Rhi/Rlo (3 MB) + CT/RT (1.5 MB) + Wc/Wr (1 MB)
  const size_t szS1 = (size_t)LSEQ * LSEQ * 4;
  const size_t szH1 = (size_t)LSEQ * DMODEL * 2;
  const size_t szW1 = (size_t)LSEQ * LSEQ * 2;
  const size_t perBatch = 2 * szS1 + 6 * szH1 + 2 * szW1;
  int nbc = (int)(ws_size / perBatch);
  if (nbc > BATCH) nbc = BATCH;
  if (nbc < 1) nbc = 1;

  char* base = (char*)d_ws;
  const size_t szS = (size_t)nbc * szS1;
  const size_t szH = (size_t)nbc * szH1;
  const size_t szW = (size_t)nbc * szW1;
  float* S = (float*)base;
  float* ST = (float*)(base + szS);
  unsigned short* Chi = (unsigned short*)(base + 2 * szS);
  unsigned short* Clo = (unsigned short*)(base + 2 * szS + szH);
  unsigned short* Rhi = (unsigned short*)(base + 2 * szS + 2 * szH);
  unsigned short* Rlo = (unsigned short*)(base + 2 * szS + 3 * szH);
  unsigned short* CT  = (unsigned short*)(base + 2 * szS + 4 * szH);
  unsigned short* RT  = (unsigned short*)(base + 2 * szS + 5 * szH);
  unsigned short* Wc  = (unsigned short*)(base + 2 * szS + 6 * szH);
  unsigned short* Wr  = (unsigned short*)(base + 2 * szS + 6 * szH + szW);

  for (int b0 = 0; b0 < BATCH; b0 += nbc) {
    int nb = BATCH - b0;
    if (nb > nbc) nb = nbc;
    dim3 blk(256);
    k_prep<<<dim3(8, 24, nb), blk, 0, stream>>>(response, context, Rhi, Rlo, RT, Chi, Clo, CT, b0);
    k_gemm_s<<<dim3(4, 4, nb), blk, 0, stream>>>(Chi, Clo, Rhi, Rlo, S, ST);
    k_softmax<<<dim3(8, 2, nb), blk, 0, stream>>>(S, ST, rmask, cmask, Wc, Wr, b0);
    k_pv<<<dim3(4, 12, nb), blk, 0, stream>>>(Wc, Wr, RT, CT, cmask, rmask, out, b0);
  }
}

// Round 4
// 317.959 us; speedup vs baseline: 1.4113x; 1.4113x over previous
//
#include <hip/hip_runtime.h>
#include <hip/hip_bf16.h>

// SoftmaxAttention: B=64, Lc=Lr=512, D=768, fp32 in/out.
// Pipeline (per batch chunk):
//   k_prep   : X fp32 -> XT fp16 [d][n] (for PV B-operand)
//   k_gemm_s : S = (Chi+Clo) * fp16(R)^T  (2-term fp16 split MFMA, fp32 acc)
//   k_softmax: job0 row-softmax(S,rmask)->Wc fp16; job1 col-softmax(S,cmask)->Wr fp16
//   k_pv     : out_c = Wc@R * cmask ; out_r = Wr@C * rmask
// Mask semantics: w_j = m_j exp(t_j - M) / (S_act + EPS*Z),
//   t = s*m, M = max_j t_j (=max(max_act,0) if any inactive),
//   Z = S_act + n_inact*exp(-M), EPS=1e-13.
// LDS tiles are [row][32 f16] (64B rows); frag reads use granule XOR swizzle
//   slot(r,g) = g ^ ((r>>1)&3)  -> 2-way bank aliasing (free).

#define BATCH 64
#define LSEQ 512
#define DMODEL 768

typedef __attribute__((ext_vector_type(4))) float f32x4;
typedef __attribute__((ext_vector_type(8))) _Float16 f16x8;
typedef __attribute__((ext_vector_type(4))) unsigned short u16x4;
typedef __attribute__((ext_vector_type(8))) unsigned short u16x8;

__device__ __forceinline__ unsigned short h2u(_Float16 h) {
  union { _Float16 h; unsigned short u; } v; v.h = h; return v.u;
}
__device__ __forceinline__ void gload16(const void* g, void* l) {
  __builtin_amdgcn_global_load_lds(
      (const __attribute__((address_space(1))) unsigned int*)g,
      (__attribute__((address_space(3))) unsigned int*)l, 16, 0, 0);
}
// byte offset into a [row][32 f16] LDS tile, granule-swizzled (16B granules)
__device__ __forceinline__ int swz(int row, int g) {
  return row * 64 + ((g ^ ((row >> 1) & 3)) << 4);
}
__device__ __forceinline__ f32x4 mfma16(f16x8 a, f16x8 b, f32x4 c) {
  return __builtin_amdgcn_mfma_f32_16x16x32_f16(a, b, c, 0, 0, 0);
}

// ---- prep: X [b][512 n][768 d] fp32 -> XT [bz][768 d][512 n] fp16 ----
// grid (8 n-tiles, 24: y<12 R d-tile, y>=12 C d-tile, nb)
__global__ __launch_bounds__(256) void k_prep(
    const float* __restrict__ Rg, const float* __restrict__ Cg,
    unsigned short* __restrict__ RT, unsigned short* __restrict__ CT, int b0) {
  __shared__ float tile[64][65];
  const int bz = blockIdx.z;
  int y = blockIdx.y;
  const float* X;
  unsigned short* XT;
  if (y < 12) { X = Rg; XT = RT; } else { y -= 12; X = Cg; XT = CT; }
  const int n0 = blockIdx.x * 64, d0 = y * 64;
  const int tid = threadIdx.x;
  const int i = tid >> 2, s4 = (tid & 3) * 4;
  const float* Xb = X + ((size_t)(b0 + bz) * LSEQ + n0 + i) * DMODEL + d0;
#pragma unroll
  for (int kk = 0; kk < 4; ++kk) {
    const int j = kk * 16 + s4;
    const f32x4 v = *(const f32x4*)(Xb + j);
#pragma unroll
    for (int k = 0; k < 4; ++k) tile[i][j + k] = v[k];
  }
  __syncthreads();
  unsigned short* Ob = XT + ((size_t)bz * DMODEL + d0 + i) * LSEQ + n0;
#pragma unroll
  for (int kk = 0; kk < 4; ++kk) {
    const int n = kk * 16 + s4;
    u16x4 h;
#pragma unroll
    for (int k = 0; k < 4; ++k) h[k] = h2u((_Float16)tile[n + k][i]);
    *(u16x4*)(Ob + n) = h;
  }
}

// ---- S[bz][c][r] = sum_d C*R, fp32 in, 2-term fp16 split, 128x128, BK=32 ----
// 1-D grid 16*nb, XCD-chunked
__global__ __launch_bounds__(256) void k_gemm_s(
    const float* __restrict__ Cg, const float* __restrict__ Rg,
    float* __restrict__ S, int b0, int nb) {
  __shared__ __align__(16) unsigned short Ahi[128 * 32];
  __shared__ __align__(16) unsigned short Alo[128 * 32];
  __shared__ __align__(16) unsigned short Bhi[128 * 32];
  const int nwg = 16 * nb;
  const int fid = blockIdx.x;
  const int nid = (fid & 7) * (nwg >> 3) + (fid >> 3);  // bijective: nwg%8==0
  const int bz = nid >> 4;
  const int c0 = (nid & 3) * 128;
  const int r0 = ((nid >> 2) & 3) * 128;
  const int tid = threadIdx.x;
  const int lane = tid & 63;
  const int w = tid >> 6;
  const int wm = (w & 1) * 64, wr = (w >> 1) * 64;
  const int l15 = lane & 15, kg = lane >> 4;
  const int srow = tid >> 2, sg = tid & 3;
  const float* Ca = Cg + ((size_t)(b0 + bz) * LSEQ + c0 + srow) * DMODEL + sg * 8;
  const float* Ca2 = Ca + (size_t)64 * DMODEL;
  const float* Ra = Rg + ((size_t)(b0 + bz) * LSEQ + r0 + srow) * DMODEL + sg * 8;
  const float* Ra2 = Ra + (size_t)64 * DMODEL;
  char* AhiB = (char*)Ahi;
  char* AloB = (char*)Alo;
  char* BhiB = (char*)Bhi;
  const int wA0 = swz(srow, sg), wA1 = swz(srow + 64, sg);
  f32x4 acc[4][4] = {};
  for (int k0 = 0; k0 < DMODEL; k0 += 32) {
    // issue global loads early (overlap prev iter's MFMA)
    const f32x4 a0a = *(const f32x4*)(Ca + k0);
    const f32x4 a0b = *(const f32x4*)(Ca + k0 + 4);
    const f32x4 a1a = *(const f32x4*)(Ca2 + k0);
    const f32x4 a1b = *(const f32x4*)(Ca2 + k0 + 4);
    const f32x4 b0a = *(const f32x4*)(Ra + k0);
    const f32x4 b0b = *(const f32x4*)(Ra + k0 + 4);
    const f32x4 b1a = *(const f32x4*)(Ra2 + k0);
    const f32x4 b1b = *(const f32x4*)(Ra2 + k0 + 4);
    f16x8 h0, l0, h1, l1, bh0, bh1;
#pragma unroll
    for (int k = 0; k < 4; ++k) {
      float x = a0a[k]; _Float16 h = (_Float16)x; h0[k] = h; l0[k] = (_Float16)(x - (float)h);
      x = a0b[k]; h = (_Float16)x; h0[4 + k] = h; l0[4 + k] = (_Float16)(x - (float)h);
      x = a1a[k]; h = (_Float16)x; h1[k] = h; l1[k] = (_Float16)(x - (float)h);
      x = a1b[k]; h = (_Float16)x; h1[4 + k] = h; l1[4 + k] = (_Float16)(x - (float)h);
      bh0[k] = (_Float16)b0a[k]; bh0[4 + k] = (_Float16)b0b[k];
      bh1[k] = (_Float16)b1a[k]; bh1[4 + k] = (_Float16)b1b[k];
    }
    __syncthreads();  // prev iter's frag reads done
    *(f16x8*)(AhiB + wA0) = h0;
    *(f16x8*)(AloB + wA0) = l0;
    *(f16x8*)(AhiB + wA1) = h1;
    *(f16x8*)(AloB + wA1) = l1;
    *(f16x8*)(BhiB + wA0) = bh0;
    *(f16x8*)(BhiB + wA1) = bh1;
    __syncthreads();
    f16x8 ah[4], al[4], bh[4];
#pragma unroll
    for (int f = 0; f < 4; ++f) {
      ah[f] = *(const f16x8*)(AhiB + swz(wm + f * 16 + l15, kg));
      al[f] = *(const f16x8*)(AloB + swz(wm + f * 16 + l15, kg));
      bh[f] = *(const f16x8*)(BhiB + swz(wr + f * 16 + l15, kg));
    }
#pragma unroll
    for (int fm = 0; fm < 4; ++fm)
#pragma unroll
      for (int fr = 0; fr < 4; ++fr) {
        acc[fm][fr] = mfma16(ah[fm], bh[fr], acc[fm][fr]);
        acc[fm][fr] = mfma16(al[fm], bh[fr], acc[fm][fr]);
      }
  }
  const int g4 = (lane >> 4) * 4;
  float* Sb = S + ((size_t)bz * LSEQ + c0) * LSEQ + r0;
#pragma unroll
  for (int fm = 0; fm < 4; ++fm)
#pragma unroll
    for (int fr = 0; fr < 4; ++fr)
#pragma unroll
      for (int reg = 0; reg < 4; ++reg)
        Sb[(size_t)(wm + fm * 16 + g4 + reg) * LSEQ + wr + fr * 16 + l15] = acc[fm][fr][reg];
}

// ---- masked softmax. job0: rows of S (mask=rmask) -> Wc[c][r] fp16 (1 pass).
//      job1: cols of S (mask=cmask) -> Wr[r][c] fp16 (online stats + write pass,
//            64x64 LDS-transposed tiles). grid (8, 2, nb)
__global__ __launch_bounds__(256) void k_softmax(
    const float* __restrict__ Sg, const int* __restrict__ rmask,
    const int* __restrict__ cmask, unsigned short* __restrict__ WcG,
    unsigned short* __restrict__ WrG, int b0) {
  __shared__ float maskNf[LSEQ];
  __shared__ float s_ninact;
  __shared__ float LT[64 * 68];  // [c_local][r_local]
  __shared__ float Msub[4][64], Ssub[4][64], Mrow[64], Invr[64];
  const int job = blockIdx.y;
  const int bz = blockIdx.z;
  const int b = b0 + bz;
  const int tid = threadIdx.x;
  const int lane = tid & 63;
  const int w = tid >> 6;
  const int* maskN = job ? cmask : rmask;
  if (tid == 0) s_ninact = 0.f;
  __syncthreads();
  float cnt = 0.f;
  for (int j = tid; j < LSEQ; j += 256) {
    const float m = (float)maskN[(size_t)b * LSEQ + j];
    maskNf[j] = m;
    cnt += 1.f - m;
  }
#pragma unroll
  for (int s = 1; s < 64; s <<= 1) cnt += __shfl_xor(cnt, s);
  if (lane == 0) atomicAdd(&s_ninact, cnt);
  __syncthreads();
  const float ninact = s_ninact;

  if (job == 0) {
    // -------- row path: 16 rows per wave, full row in registers --------
    const int r0 = blockIdx.x * 64;
    float mk[8];
#pragma unroll
    for (int k = 0; k < 8; ++k) mk[k] = maskNf[lane * 8 + k];
    for (int rr = 0; rr < 16; ++rr) {
      const int r = r0 + w * 16 + rr;
      const float* Lr = Sg + ((size_t)bz * LSEQ + r) * LSEQ + lane * 8;
      const f32x4 v0 = *(const f32x4*)(Lr);
      const f32x4 v1 = *(const f32x4*)(Lr + 4);
      float v[8];
#pragma unroll
      for (int k = 0; k < 4; ++k) { v[k] = v0[k]; v[k + 4] = v1[k]; }
      float mx = -1e30f;
#pragma unroll
      for (int k = 0; k < 8; ++k)
        if (mk[k] > 0.5f) mx = fmaxf(mx, v[k]);
#pragma unroll
      for (int s = 1; s < 64; s <<= 1) mx = fmaxf(mx, __shfl_xor(mx, s));
      const float M = (ninact > 0.5f) ? fmaxf(mx, 0.f) : mx;
      float p[8];
      float sum = 0.f;
#pragma unroll
      for (int k = 0; k < 8; ++k) {
        p[k] = mk[k] * __expf(fminf(v[k] - M, 0.f));
        sum += p[k];
      }
#pragma unroll
      for (int s = 1; s < 64; s <<= 1) sum += __shfl_xor(sum, s);
      const float Z = sum + ((ninact > 0.5f) ? ninact * __expf(-M) : 0.f);
      const float inv = 1.f / (sum + 1e-13f * Z);
      u16x8 h;
#pragma unroll
      for (int k = 0; k < 8; ++k) h[k] = h2u((_Float16)(p[k] * inv));
      *(u16x8*)(WcG + ((size_t)bz * LSEQ + r) * LSEQ + lane * 8) = h;
    }
    return;
  }
  // -------- col path: 64 r-columns, online stats then write pass --------
  const int r0 = blockIdx.x * 64;
  const float* Sb = Sg + (size_t)bz * LSEQ * LSEQ;
  const int sti = tid >> 2, stj = (tid & 3) * 16;  // staging role
  {
    const int rl = tid & 63, cs = w;  // stats role: 4 c-quarters per r
    float m = -1e30f, s = 0.f;
    for (int ct = 0; ct < 8; ++ct) {
      __syncthreads();  // prev tile reads done
      const float* src = Sb + (size_t)(ct * 64 + sti) * LSEQ + r0 + stj;
#pragma unroll
      for (int q = 0; q < 4; ++q)
        *(f32x4*)&LT[sti * 68 + stj + q * 4] = *(const f32x4*)(src + q * 4);
      __syncthreads();
      const int cb = ct * 64 + cs * 16;
      float v[16];
#pragma unroll
      for (int q = 0; q < 16; ++q) v[q] = LT[(cs * 16 + q) * 68 + rl];
      float tm = -1e30f;
#pragma unroll
      for (int q = 0; q < 16; ++q)
        if (maskNf[cb + q] > 0.5f) tm = fmaxf(tm, v[q]);
      const float nm = fmaxf(m, tm);
      s *= __expf(fminf(m - nm, 0.f));
#pragma unroll
      for (int q = 0; q < 16; ++q)
        s += maskNf[cb + q] * __expf(fminf(v[q] - nm, 0.f));
      m = nm;
    }
    Msub[cs][rl] = m;
    Ssub[cs][rl] = s;
  }
  __syncthreads();
  if (tid < 64) {
    float M = -1e30f;
#pragma unroll
    for (int c = 0; c < 4; ++c) M = fmaxf(M, Msub[c][tid]);
    float s = 0.f;
#pragma unroll
    for (int c = 0; c < 4; ++c)
      s += Ssub[c][tid] * __expf(fminf(Msub[c][tid] - M, 0.f));
    const float Mf = (ninact > 0.5f) ? fmaxf(M, 0.f) : M;
    s *= __expf(fminf(M - Mf, 0.f));
    const float Z = s + ((ninact > 0.5f) ? ninact * __expf(-Mf) : 0.f);
    Mrow[tid] = Mf;
    Invr[tid] = 1.f / (s + 1e-13f * Z);
  }
  const int rl2 = tid >> 2, cs2 = tid & 3;  // write role
  for (int ct = 0; ct < 8; ++ct) {
    __syncthreads();  // stats ready (ct=0) / prev tile reads done
    const float* src = Sb + (size_t)(ct * 64 + sti) * LSEQ + r0 + stj;
#pragma unroll
    for (int q = 0; q < 4; ++q)
      *(f32x4*)&LT[sti * 68 + stj + q * 4] = *(const f32x4*)(src + q * 4);
    __syncthreads();
    const float M = Mrow[rl2], inv = Invr[rl2];
    const int cb = ct * 64 + cs2 * 16;
    u16x8 h0, h1;
#pragma unroll
    for (int q = 0; q < 16; ++q) {
      const float p =
          maskNf[cb + q] * __expf(fminf(LT[(cs2 * 16 + q) * 68 + rl2] - M, 0.f)) * inv;
      if (q < 8) h0[q] = h2u((_Float16)p);
      else h1[q - 8] = h2u((_Float16)p);
    }
    unsigned short* dst = WrG + ((size_t)bz * LSEQ + r0 + rl2) * LSEQ + cb;
    *(u16x8*)dst = h0;
    *(u16x8*)(dst + 8) = h1;
  }
}

// ---- PV: out[b][m][d] = (sum_n W[m,n]*Vt[d,n]) * maskM[m], fp16 MFMA ----
// 1-D grid 48*nb, XCD-chunked; 128x128 tile, BK=32, gload_lds w/ source preswizzle
__global__ __launch_bounds__(256) void k_pv(
    const unsigned short* __restrict__ WcG, const unsigned short* __restrict__ WrG,
    const unsigned short* __restrict__ RT, const unsigned short* __restrict__ CT,
    const int* __restrict__ cmask, const int* __restrict__ rmask,
    float* __restrict__ out, int b0, int nb) {
  __shared__ __align__(16) unsigned short Alds[128 * 32];
  __shared__ __align__(16) unsigned short Blds[128 * 32];
  __shared__ float maskMf[128];
  const int nwg = 48 * nb;
  const int fid = blockIdx.x;
  const int nid = (fid & 7) * (nwg >> 3) + (fid >> 3);
  const int bz = nid / 48;
  const int rem = nid % 48;
  const int m0 = (rem & 3) * 128;
  int y = rem >> 2;
  const int job = (y >= 6) ? 1 : 0;
  if (job) y -= 6;
  const unsigned short* Wg = job ? WrG : WcG;
  const unsigned short* Vt = job ? CT : RT;
  const int* maskM = job ? rmask : cmask;
  float* outp = out + (job ? (size_t)BATCH * LSEQ * DMODEL : 0);
  const int d0 = y * 128;
  const int tid = threadIdx.x;
  const int lane = tid & 63;
  const int w = tid >> 6;
  const int wm = (w & 1) * 64, wd = (w >> 1) * 64;
  const int l15 = lane & 15, kg = lane >> 4;
  if (tid < 128) maskMf[tid] = (float)maskM[(size_t)(b0 + bz) * LSEQ + m0 + tid];
  const unsigned short* Wb = Wg + ((size_t)bz * LSEQ + m0) * LSEQ;
  const unsigned short* Vb = Vt + ((size_t)bz * DMODEL + d0) * LSEQ;
  f32x4 acc[4][4] = {};
  for (int k0 = 0; k0 < LSEQ; k0 += 32) {
    __syncthreads();
#pragma unroll
    for (int q = 0; q < 2; ++q) {
      const int t2 = q * 256 + tid;
      const int row = t2 >> 2, gp = t2 & 3;
      const int gs = gp ^ ((row >> 1) & 3);  // source granule preswizzle
      gload16(Wb + (size_t)row * LSEQ + k0 + gs * 8, &Alds[t2 * 8]);
      gload16(Vb + (size_t)row * LSEQ + k0 + gs * 8, &Blds[t2 * 8]);
    }
    __syncthreads();
    f16x8 a[4], bb[4];
#pragma unroll
    for (int f = 0; f < 4; ++f) {
      a[f] = *(const f16x8*)((const char*)Alds + swz(wm + f * 16 + l15, kg));
      bb[f] = *(const f16x8*)((const char*)Blds + swz(wd + f * 16 + l15, kg));
    }
#pragma unroll
    for (int fm = 0; fm < 4; ++fm)
#pragma unroll
      for (int fd = 0; fd < 4; ++fd)
        acc[fm][fd] = mfma16(a[fm], bb[fd], acc[fm][fd]);
  }
  const int g4 = (lane >> 4) * 4;
#pragma unroll
  for (int fm = 0; fm < 4; ++fm)
#pragma unroll
    for (int fd = 0; fd < 4; ++fd)
#pragma unroll
      for (int reg = 0; reg < 4; ++reg) {
        const int row = wm + fm * 16 + g4 + reg;
        const int col = wd + fd * 16 + l15;
        outp[((size_t)(b0 + bz) * LSEQ + m0 + row) * DMODEL + d0 + col] =
            acc[fm][fd][reg] * maskMf[row];
      }
}

extern "C" void kernel_launch(void* const* d_in, const int* in_sizes, int n_in,
                              void* d_out, int out_size, void* d_ws, size_t ws_size,
                              hipStream_t stream) {
  const float* context = (const float*)d_in[0];
  const float* response = (const float*)d_in[1];
  const int* cmask = (const int*)d_in[2];
  const int* rmask = (const int*)d_in[3];
  float* out = (float*)d_out;

  // per-batch ws: S fp32 1MB + RT/CT fp16 0.75MB each + Wc/Wr fp16 0.5MB each
  const size_t szS1 = (size_t)LSEQ * LSEQ * 4;
  const size_t szT1 = (size_t)LSEQ * DMODEL * 2;
  const size_t szW1 = (size_t)LSEQ * LSEQ * 2;
  const size_t perBatch = szS1 + 2 * szT1 + 2 * szW1;
  int nbc = (int)(ws_size / perBatch);
  if (nbc > BATCH) nbc = BATCH;
  if (nbc < 1) nbc = 1;

  char* base = (char*)d_ws;
  const size_t szS = (size_t)nbc * szS1;
  const size_t szT = (size_t)nbc * szT1;
  const size_t szW = (size_t)nbc * szW1;
  float* S = (float*)base;
  unsigned short* RT = (unsigned short*)(base + szS);
  unsigned short* CT = (unsigned short*)(base + szS + szT);
  unsigned short* Wc = (unsigned short*)(base + szS + 2 * szT);
  unsigned short* Wr = (unsigned short*)(base + szS + 2 * szT + szW);

  for (int b0 = 0; b0 < BATCH; b0 += nbc) {
    int nb = BATCH - b0;
    if (nb > nbc) nb = nbc;
    dim3 blk(256);
    k_prep<<<dim3(8, 24, nb), blk, 0, stream>>>(response, context, RT, CT, b0);
    k_gemm_s<<<dim3(16 * nb), blk, 0, stream>>>(context, response, S, b0, nb);
    k_softmax<<<dim3(8, 2, nb), blk, 0, stream>>>(S, rmask, cmask, Wc, Wr, b0);
    k_pv<<<dim3(48 * nb), blk, 0, stream>>>(Wc, Wr, RT, CT, cmask, rmask, out, b0, nb);
  }
}

// Round 5
// 306.235 us; speedup vs baseline: 1.4653x; 1.0383x over previous
//
#include <hip/hip_runtime.h>
#include <hip/hip_bf16.h>

// SoftmaxAttention: B=64, Lc=Lr=512, D=768, fp32 in/out.
// Pipeline (per batch chunk):
//   k_prep   : X fp32 -> XT fp16 [d][n] (for PV B-operand)
//   k_gemm_s : S = (Chi+Clo) * fp16(R)^T  (2-term fp16 split MFMA, fp32 acc)
//              with register prefetch of next K-step (load latency under MFMA)
//   k_softmax: job0 row-softmax(S,rmask)->Wc fp16; job1 col-softmax(S,cmask)->Wr fp16
//   k_pv     : out_c = Wc@R * cmask ; out_r = Wr@C * rmask
//              double-buffered LDS, 2-phase: stage(next) || compute(cur), 1 barrier/iter
// Mask semantics: w_j = m_j exp(t_j - M) / (S_act + EPS*Z),
//   t = s*m, M = max_j t_j (=max(max_act,0) if any inactive),
//   Z = S_act + n_inact*exp(-M), EPS=1e-13.
// LDS tiles are [row][32 f16] (64B rows); frag reads use granule XOR swizzle
//   slot(r,g) = g ^ ((r>>1)&3)  -> 2-way bank aliasing (free).

#define BATCH 64
#define LSEQ 512
#define DMODEL 768

typedef __attribute__((ext_vector_type(4))) float f32x4;
typedef __attribute__((ext_vector_type(8))) _Float16 f16x8;
typedef __attribute__((ext_vector_type(4))) unsigned short u16x4;
typedef __attribute__((ext_vector_type(8))) unsigned short u16x8;

__device__ __forceinline__ unsigned short h2u(_Float16 h) {
  union { _Float16 h; unsigned short u; } v; v.h = h; return v.u;
}
__device__ __forceinline__ void gload16(const void* g, void* l) {
  __builtin_amdgcn_global_load_lds(
      (const __attribute__((address_space(1))) unsigned int*)g,
      (__attribute__((address_space(3))) unsigned int*)l, 16, 0, 0);
}
// byte offset into a [row][32 f16] LDS tile, granule-swizzled (16B granules)
__device__ __forceinline__ int swz(int row, int g) {
  return row * 64 + ((g ^ ((row >> 1) & 3)) << 4);
}
__device__ __forceinline__ f32x4 mfma16(f16x8 a, f16x8 b, f32x4 c) {
  return __builtin_amdgcn_mfma_f32_16x16x32_f16(a, b, c, 0, 0, 0);
}

// ---- prep: X [b][512 n][768 d] fp32 -> XT [bz][768 d][512 n] fp16 ----
// grid (8 n-tiles, 24: y<12 R d-tile, y>=12 C d-tile, nb)
__global__ __launch_bounds__(256) void k_prep(
    const float* __restrict__ Rg, const float* __restrict__ Cg,
    unsigned short* __restrict__ RT, unsigned short* __restrict__ CT, int b0) {
  __shared__ float tile[64][65];
  const int bz = blockIdx.z;
  int y = blockIdx.y;
  const float* X;
  unsigned short* XT;
  if (y < 12) { X = Rg; XT = RT; } else { y -= 12; X = Cg; XT = CT; }
  const int n0 = blockIdx.x * 64, d0 = y * 64;
  const int tid = threadIdx.x;
  const int i = tid >> 2, s4 = (tid & 3) * 4;
  const float* Xb = X + ((size_t)(b0 + bz) * LSEQ + n0 + i) * DMODEL + d0;
#pragma unroll
  for (int kk = 0; kk < 4; ++kk) {
    const int j = kk * 16 + s4;
    const f32x4 v = *(const f32x4*)(Xb + j);
#pragma unroll
    for (int k = 0; k < 4; ++k) tile[i][j + k] = v[k];
  }
  __syncthreads();
  unsigned short* Ob = XT + ((size_t)bz * DMODEL + d0 + i) * LSEQ + n0;
#pragma unroll
  for (int kk = 0; kk < 4; ++kk) {
    const int n = kk * 16 + s4;
    u16x4 h;
#pragma unroll
    for (int k = 0; k < 4; ++k) h[k] = h2u((_Float16)tile[n + k][i]);
    *(u16x4*)(Ob + n) = h;
  }
}

// ---- S[bz][c][r] = sum_d C*R, fp32 in, 2-term fp16 split, 128x128, BK=32 ----
// 1-D grid 16*nb, XCD-chunked. Register prefetch of next K-step.
__global__ __launch_bounds__(256) void k_gemm_s(
    const float* __restrict__ Cg, const float* __restrict__ Rg,
    float* __restrict__ S, int b0, int nb) {
  __shared__ __align__(16) unsigned short Ahi[128 * 32];
  __shared__ __align__(16) unsigned short Alo[128 * 32];
  __shared__ __align__(16) unsigned short Bhi[128 * 32];
  const int nwg = 16 * nb;
  const int fid = blockIdx.x;
  const int nid = (fid & 7) * (nwg >> 3) + (fid >> 3);  // bijective: nwg%8==0
  const int bz = nid >> 4;
  const int c0 = (nid & 3) * 128;
  const int r0 = ((nid >> 2) & 3) * 128;
  const int tid = threadIdx.x;
  const int lane = tid & 63;
  const int w = tid >> 6;
  const int wm = (w & 1) * 64, wr = (w >> 1) * 64;
  const int l15 = lane & 15, kg = lane >> 4;
  const int srow = tid >> 2, sg = tid & 3;
  const float* Ca = Cg + ((size_t)(b0 + bz) * LSEQ + c0 + srow) * DMODEL + sg * 8;
  const float* Ca2 = Ca + (size_t)64 * DMODEL;
  const float* Ra = Rg + ((size_t)(b0 + bz) * LSEQ + r0 + srow) * DMODEL + sg * 8;
  const float* Ra2 = Ra + (size_t)64 * DMODEL;
  char* AhiB = (char*)Ahi;
  char* AloB = (char*)Alo;
  char* BhiB = (char*)Bhi;
  const int wA0 = swz(srow, sg), wA1 = swz(srow + 64, sg);
  f32x4 a0a = *(const f32x4*)(Ca);
  f32x4 a0b = *(const f32x4*)(Ca + 4);
  f32x4 a1a = *(const f32x4*)(Ca2);
  f32x4 a1b = *(const f32x4*)(Ca2 + 4);
  f32x4 b0a = *(const f32x4*)(Ra);
  f32x4 b0b = *(const f32x4*)(Ra + 4);
  f32x4 b1a = *(const f32x4*)(Ra2);
  f32x4 b1b = *(const f32x4*)(Ra2 + 4);
  f32x4 acc[4][4] = {};
  for (int k0 = 0; k0 < DMODEL; k0 += 32) {
    // convert current regs (loaded last iter; latency hidden under prev MFMA)
    f16x8 h0, l0, h1, l1, bh0, bh1;
#pragma unroll
    for (int k = 0; k < 4; ++k) {
      float x = a0a[k]; _Float16 h = (_Float16)x; h0[k] = h; l0[k] = (_Float16)(x - (float)h);
      x = a0b[k]; h = (_Float16)x; h0[4 + k] = h; l0[4 + k] = (_Float16)(x - (float)h);
      x = a1a[k]; h = (_Float16)x; h1[k] = h; l1[k] = (_Float16)(x - (float)h);
      x = a1b[k]; h = (_Float16)x; h1[4 + k] = h; l1[4 + k] = (_Float16)(x - (float)h);
      bh0[k] = (_Float16)b0a[k]; bh0[4 + k] = (_Float16)b0b[k];
      bh1[k] = (_Float16)b1a[k]; bh1[4 + k] = (_Float16)b1b[k];
    }
    __syncthreads();  // prev iter's frag reads done
    *(f16x8*)(AhiB + wA0) = h0;
    *(f16x8*)(AloB + wA0) = l0;
    *(f16x8*)(AhiB + wA1) = h1;
    *(f16x8*)(AloB + wA1) = l1;
    *(f16x8*)(BhiB + wA0) = bh0;
    *(f16x8*)(BhiB + wA1) = bh1;
    __syncthreads();
    // issue next K-step loads AFTER the last barrier: no drain between issue
    // and use; latency hides under this iter's ds_read + MFMA.
    if (k0 + 32 < DMODEL) {
      const int kn = k0 + 32;
      a0a = *(const f32x4*)(Ca + kn);
      a0b = *(const f32x4*)(Ca + kn + 4);
      a1a = *(const f32x4*)(Ca2 + kn);
      a1b = *(const f32x4*)(Ca2 + kn + 4);
      b0a = *(const f32x4*)(Ra + kn);
      b0b = *(const f32x4*)(Ra + kn + 4);
      b1a = *(const f32x4*)(Ra2 + kn);
      b1b = *(const f32x4*)(Ra2 + kn + 4);
    }
    f16x8 ah[4], al[4], bh[4];
#pragma unroll
    for (int f = 0; f < 4; ++f) {
      ah[f] = *(const f16x8*)(AhiB + swz(wm + f * 16 + l15, kg));
      al[f] = *(const f16x8*)(AloB + swz(wm + f * 16 + l15, kg));
      bh[f] = *(const f16x8*)(BhiB + swz(wr + f * 16 + l15, kg));
    }
#pragma unroll
    for (int fm = 0; fm < 4; ++fm)
#pragma unroll
      for (int fr = 0; fr < 4; ++fr) {
        acc[fm][fr] = mfma16(ah[fm], bh[fr], acc[fm][fr]);
        acc[fm][fr] = mfma16(al[fm], bh[fr], acc[fm][fr]);
      }
  }
  const int g4 = (lane >> 4) * 4;
  float* Sb = S + ((size_t)bz * LSEQ + c0) * LSEQ + r0;
#pragma unroll
  for (int fm = 0; fm < 4; ++fm)
#pragma unroll
    for (int fr = 0; fr < 4; ++fr)
#pragma unroll
      for (int reg = 0; reg < 4; ++reg)
        Sb[(size_t)(wm + fm * 16 + g4 + reg) * LSEQ + wr + fr * 16 + l15] = acc[fm][fr][reg];
}

// ---- masked softmax. job0: rows of S (mask=rmask) -> Wc[c][r] fp16 (1 pass).
//      job1: cols of S (mask=cmask) -> Wr[r][c] fp16 (online stats + write pass,
//            64x64 LDS-transposed tiles). grid (8, 2, nb)
__global__ __launch_bounds__(256) void k_softmax(
    const float* __restrict__ Sg, const int* __restrict__ rmask,
    const int* __restrict__ cmask, unsigned short* __restrict__ WcG,
    unsigned short* __restrict__ WrG, int b0) {
  __shared__ float maskNf[LSEQ];
  __shared__ float s_ninact;
  __shared__ float LT[64 * 68];  // [c_local][r_local]
  __shared__ float Msub[4][64], Ssub[4][64], Mrow[64], Invr[64];
  const int job = blockIdx.y;
  const int bz = blockIdx.z;
  const int b = b0 + bz;
  const int tid = threadIdx.x;
  const int lane = tid & 63;
  const int w = tid >> 6;
  const int* maskN = job ? cmask : rmask;
  if (tid == 0) s_ninact = 0.f;
  __syncthreads();
  float cnt = 0.f;
  for (int j = tid; j < LSEQ; j += 256) {
    const float m = (float)maskN[(size_t)b * LSEQ + j];
    maskNf[j] = m;
    cnt += 1.f - m;
  }
#pragma unroll
  for (int s = 1; s < 64; s <<= 1) cnt += __shfl_xor(cnt, s);
  if (lane == 0) atomicAdd(&s_ninact, cnt);
  __syncthreads();
  const float ninact = s_ninact;

  if (job == 0) {
    // -------- row path: 16 rows per wave, full row in registers --------
    const int r0 = blockIdx.x * 64;
    float mk[8];
#pragma unroll
    for (int k = 0; k < 8; ++k) mk[k] = maskNf[lane * 8 + k];
    for (int rr = 0; rr < 16; ++rr) {
      const int r = r0 + w * 16 + rr;
      const float* Lr = Sg + ((size_t)bz * LSEQ + r) * LSEQ + lane * 8;
      const f32x4 v0 = *(const f32x4*)(Lr);
      const f32x4 v1 = *(const f32x4*)(Lr + 4);
      float v[8];
#pragma unroll
      for (int k = 0; k < 4; ++k) { v[k] = v0[k]; v[k + 4] = v1[k]; }
      float mx = -1e30f;
#pragma unroll
      for (int k = 0; k < 8; ++k)
        if (mk[k] > 0.5f) mx = fmaxf(mx, v[k]);
#pragma unroll
      for (int s = 1; s < 64; s <<= 1) mx = fmaxf(mx, __shfl_xor(mx, s));
      const float M = (ninact > 0.5f) ? fmaxf(mx, 0.f) : mx;
      float p[8];
      float sum = 0.f;
#pragma unroll
      for (int k = 0; k < 8; ++k) {
        p[k] = mk[k] * __expf(fminf(v[k] - M, 0.f));
        sum += p[k];
      }
#pragma unroll
      for (int s = 1; s < 64; s <<= 1) sum += __shfl_xor(sum, s);
      const float Z = sum + ((ninact > 0.5f) ? ninact * __expf(-M) : 0.f);
      const float inv = 1.f / (sum + 1e-13f * Z);
      u16x8 h;
#pragma unroll
      for (int k = 0; k < 8; ++k) h[k] = h2u((_Float16)(p[k] * inv));
      *(u16x8*)(WcG + ((size_t)bz * LSEQ + r) * LSEQ + lane * 8) = h;
    }
    return;
  }
  // -------- col path: 64 r-columns, online stats then write pass --------
  const int r0 = blockIdx.x * 64;
  const float* Sb = Sg + (size_t)bz * LSEQ * LSEQ;
  const int sti = tid >> 2, stj = (tid & 3) * 16;  // staging role
  {
    const int rl = tid & 63, cs = w;  // stats role: 4 c-quarters per r
    float m = -1e30f, s = 0.f;
    for (int ct = 0; ct < 8; ++ct) {
      __syncthreads();  // prev tile reads done
      const float* src = Sb + (size_t)(ct * 64 + sti) * LSEQ + r0 + stj;
#pragma unroll
      for (int q = 0; q < 4; ++q)
        *(f32x4*)&LT[sti * 68 + stj + q * 4] = *(const f32x4*)(src + q * 4);
      __syncthreads();
      const int cb = ct * 64 + cs * 16;
      float v[16];
#pragma unroll
      for (int q = 0; q < 16; ++q) v[q] = LT[(cs * 16 + q) * 68 + rl];
      float tm = -1e30f;
#pragma unroll
      for (int q = 0; q < 16; ++q)
        if (maskNf[cb + q] > 0.5f) tm = fmaxf(tm, v[q]);
      const float nm = fmaxf(m, tm);
      s *= __expf(fminf(m - nm, 0.f));
#pragma unroll
      for (int q = 0; q < 16; ++q)
        s += maskNf[cb + q] * __expf(fminf(v[q] - nm, 0.f));
      m = nm;
    }
    Msub[cs][rl] = m;
    Ssub[cs][rl] = s;
  }
  __syncthreads();
  if (tid < 64) {
    float M = -1e30f;
#pragma unroll
    for (int c = 0; c < 4; ++c) M = fmaxf(M, Msub[c][tid]);
    float s = 0.f;
#pragma unroll
    for (int c = 0; c < 4; ++c)
      s += Ssub[c][tid] * __expf(fminf(Msub[c][tid] - M, 0.f));
    const float Mf = (ninact > 0.5f) ? fmaxf(M, 0.f) : M;
    s *= __expf(fminf(M - Mf, 0.f));
    const float Z = s + ((ninact > 0.5f) ? ninact * __expf(-Mf) : 0.f);
    Mrow[tid] = Mf;
    Invr[tid] = 1.f / (s + 1e-13f * Z);
  }
  const int rl2 = tid >> 2, cs2 = tid & 3;  // write role
  for (int ct = 0; ct < 8; ++ct) {
    __syncthreads();  // stats ready (ct=0) / prev tile reads done
    const float* src = Sb + (size_t)(ct * 64 + sti) * LSEQ + r0 + stj;
#pragma unroll
    for (int q = 0; q < 4; ++q)
      *(f32x4*)&LT[sti * 68 + stj + q * 4] = *(const f32x4*)(src + q * 4);
    __syncthreads();
    const float M = Mrow[rl2], inv = Invr[rl2];
    const int cb = ct * 64 + cs2 * 16;
    u16x8 h0, h1;
#pragma unroll
    for (int q = 0; q < 16; ++q) {
      const float p =
          maskNf[cb + q] * __expf(fminf(LT[(cs2 * 16 + q) * 68 + rl2] - M, 0.f)) * inv;
      if (q < 8) h0[q] = h2u((_Float16)p);
      else h1[q - 8] = h2u((_Float16)p);
    }
    unsigned short* dst = WrG + ((size_t)bz * LSEQ + r0 + rl2) * LSEQ + cb;
    *(u16x8*)dst = h0;
    *(u16x8*)(dst + 8) = h1;
  }
}

// ---- PV: out[b][m][d] = (sum_n W[m,n]*Vt[d,n]) * maskM[m], fp16 MFMA ----
// 1-D grid 48*nb, XCD-chunked; 128x128 tile, BK=32, DOUBLE-BUFFERED LDS:
// per iter: stage(buf^1, t+1) -> ds_read/MFMA(buf) -> one barrier (drains loads
// after they've flown under compute).
__global__ __launch_bounds__(256) void k_pv(
    const unsigned short* __restrict__ WcG, const unsigned short* __restrict__ WrG,
    const unsigned short* __restrict__ RT, const unsigned short* __restrict__ CT,
    const int* __restrict__ cmask, const int* __restrict__ rmask,
    float* __restrict__ out, int b0, int nb) {
  __shared__ __align__(16) unsigned short Alds[2][128 * 32];
  __shared__ __align__(16) unsigned short Blds[2][128 * 32];
  __shared__ float maskMf[128];
  const int nwg = 48 * nb;
  const int fid = blockIdx.x;
  const int nid = (fid & 7) * (nwg >> 3) + (fid >> 3);
  const int bz = nid / 48;
  const int rem = nid % 48;
  const int m0 = (rem & 3) * 128;
  int y = rem >> 2;
  const int job = (y >= 6) ? 1 : 0;
  if (job) y -= 6;
  const unsigned short* Wg = job ? WrG : WcG;
  const unsigned short* Vt = job ? CT : RT;
  const int* maskM = job ? rmask : cmask;
  float* outp = out + (job ? (size_t)BATCH * LSEQ * DMODEL : 0);
  const int d0 = y * 128;
  const int tid = threadIdx.x;
  const int lane = tid & 63;
  const int w = tid >> 6;
  const int wm = (w & 1) * 64, wd = (w >> 1) * 64;
  const int l15 = lane & 15, kg = lane >> 4;
  if (tid < 128) maskMf[tid] = (float)maskM[(size_t)(b0 + bz) * LSEQ + m0 + tid];
  const unsigned short* Wb = Wg + ((size_t)bz * LSEQ + m0) * LSEQ;
  const unsigned short* Vb = Vt + ((size_t)bz * DMODEL + d0) * LSEQ;
  // per-thread staging coords: rows sr and sr+64, source granule preswizzled
  const int sr = tid >> 2, gp = tid & 3;
  const int gs0 = (gp ^ ((sr >> 1) & 3)) * 8;
  const int gs1 = (gp ^ (((sr + 64) >> 1) & 3)) * 8;

#define PV_STAGE(buf, k0)                                             \
  do {                                                                \
    gload16(Wb + (size_t)sr * LSEQ + (k0) + gs0, &Alds[buf][tid * 8]);\
    gload16(Vb + (size_t)sr * LSEQ + (k0) + gs0, &Blds[buf][tid * 8]);\
    gload16(Wb + (size_t)(sr + 64) * LSEQ + (k0) + gs1,               \
            &Alds[buf][(256 + tid) * 8]);                             \
    gload16(Vb + (size_t)(sr + 64) * LSEQ + (k0) + gs1,               \
            &Blds[buf][(256 + tid) * 8]);                             \
  } while (0)

  f32x4 acc[4][4] = {};
  PV_STAGE(0, 0);
  __syncthreads();  // first tile resident
  int cur = 0;
  for (int t = 0; t < 16; ++t) {
    if (t < 15) PV_STAGE(cur ^ 1, (t + 1) * 32);  // fly under compute
    f16x8 a[4], bb[4];
#pragma unroll
    for (int f = 0; f < 4; ++f) {
      a[f] = *(const f16x8*)((const char*)Alds[cur] + swz(wm + f * 16 + l15, kg));
      bb[f] = *(const f16x8*)((const char*)Blds[cur] + swz(wd + f * 16 + l15, kg));
    }
#pragma unroll
    for (int fm = 0; fm < 4; ++fm)
#pragma unroll
      for (int fd = 0; fd < 4; ++fd)
        acc[fm][fd] = mfma16(a[fm], bb[fd], acc[fm][fd]);
    __syncthreads();  // drains next-tile loads + all reads of cur done
    cur ^= 1;
  }
#undef PV_STAGE
  const int g4 = (lane >> 4) * 4;
#pragma unroll
  for (int fm = 0; fm < 4; ++fm)
#pragma unroll
    for (int fd = 0; fd < 4; ++fd)
#pragma unroll
      for (int reg = 0; reg < 4; ++reg) {
        const int row = wm + fm * 16 + g4 + reg;
        const int col = wd + fd * 16 + l15;
        outp[((size_t)(b0 + bz) * LSEQ + m0 + row) * DMODEL + d0 + col] =
            acc[fm][fd][reg] * maskMf[row];
      }
}

extern "C" void kernel_launch(void* const* d_in, const int* in_sizes, int n_in,
                              void* d_out, int out_size, void* d_ws, size_t ws_size,
                              hipStream_t stream) {
  const float* context = (const float*)d_in[0];
  const float* response = (const float*)d_in[1];
  const int* cmask = (const int*)d_in[2];
  const int* rmask = (const int*)d_in[3];
  float* out = (float*)d_out;

  // per-batch ws: S fp32 1MB + RT/CT fp16 0.75MB each + Wc/Wr fp16 0.5MB each
  const size_t szS1 = (size_t)LSEQ * LSEQ * 4;
  const size_t szT1 = (size_t)LSEQ * DMODEL * 2;
  const size_t szW1 = (size_t)LSEQ * LSEQ * 2;
  const size_t perBatch = szS1 + 2 * szT1 + 2 * szW1;
  int nbc = (int)(ws_size / perBatch);
  if (nbc > BATCH) nbc = BATCH;
  if (nbc < 1) nbc = 1;

  char* base = (char*)d_ws;
  const size_t szS = (size_t)nbc * szS1;
  const size_t szT = (size_t)nbc * szT1;
  const size_t szW = (size_t)nbc * szW1;
  float* S = (float*)base;
  unsigned short* RT = (unsigned short*)(base + szS);
  unsigned short* CT = (unsigned short*)(base + szS + szT);
  unsigned short* Wc = (unsigned short*)(base + szS + 2 * szT);
  unsigned short* Wr = (unsigned short*)(base + szS + 2 * szT + szW);

  for (int b0 = 0; b0 < BATCH; b0 += nbc) {
    int nb = BATCH - b0;
    if (nb > nbc) nb = nbc;
    dim3 blk(256);
    k_prep<<<dim3(8, 24, nb), blk, 0, stream>>>(response, context, RT, CT, b0);
    k_gemm_s<<<dim3(16 * nb), blk, 0, stream>>>(context, response, S, b0, nb);
    k_softmax<<<dim3(8, 2, nb), blk, 0, stream>>>(S, rmask, cmask, Wc, Wr, b0);
    k_pv<<<dim3(48 * nb), blk, 0, stream>>>(Wc, Wr, RT, CT, cmask, rmask, out, b0, nb);
  }
}